// Round 2
// baseline (741.467 us; speedup 1.0000x reference)
//
#include <hip/hip_runtime.h>
#include <hip/hip_cooperative_groups.h>

namespace cg = cooperative_groups;

typedef float f32x4 __attribute__((ext_vector_type(4)));

// Problem constants: B=32, N=8, Lq=256, Ld=512, D=768
#define BB 32
#define NN 8
#define LQ 256
#define LD 512
#define DD 768
#define D4 (DD / 4)                   // 192 float4 per row

#define QCH 8                         // lq chunks in qsum phase
#define QROWS (LQ / QCH)              // 32 rows per qsum block
#define QPART_ELEMS (QCH * BB * DD)   // 196608 floats in ws

#define CH 4                          // l-chunks per (b,n) doc
#define LCHUNK (LD / CH)              // 128 rows per block
#define NBLK (BB * NN * CH)           // 1024 blocks == grid size (all resident)

// ---------------------------------------------------------------------------
// Single cooperative kernel: phase 1 (q row-sums) -> grid.sync ->
// phase 2 (stream docs once, dot with qv) -> grid.sync -> phase 3 (reduce).
// 1024 blocks x 192 threads = 12 waves/CU; __launch_bounds__(192,4) caps
// VGPR at 128 so residency (4 blocks/CU needed, 5 fit) is guaranteed.
// Regular cached loads everywhere: m13's 6.29 TB/s ceiling used regular
// loads; qpart is L2-hot at each use point (written/read around syncs).
// ---------------------------------------------------------------------------
__global__ void __launch_bounds__(192, 4)
fused_kernel(const float* __restrict__ q, const float* __restrict__ docs,
             const int* __restrict__ is_ans, float* __restrict__ qpart,
             float* __restrict__ partials, float* __restrict__ out) {
    cg::grid_group grid = cg::this_grid();
    const int blk = blockIdx.x;
    const int t   = threadIdx.x;      // 0..191 float4 column
    __shared__ float wsum[3];

    // ---- Phase 1: qpart[c][b][:] = sum of 32 q rows (blocks 0..255) ----
    if (blk < BB * QCH) {
        int b = blk >> 3;             // 0..31
        int c = blk & 7;              // 0..7
        const f32x4* p = (const f32x4*)(q + ((size_t)b * LQ + (size_t)c * QROWS) * DD) + t;
        f32x4 z = {0.f, 0.f, 0.f, 0.f};
        f32x4 acc[8];
#pragma unroll
        for (int i = 0; i < 8; ++i) acc[i] = z;
#pragma unroll 2
        for (int i0 = 0; i0 < QROWS; i0 += 8) {
            f32x4 v[8];
#pragma unroll
            for (int k = 0; k < 8; ++k) v[k] = p[(size_t)(i0 + k) * D4];
#pragma unroll
            for (int k = 0; k < 8; ++k) acc[k] += v[k];
        }
        f32x4 r = ((acc[0] + acc[1]) + (acc[2] + acc[3])) +
                  ((acc[4] + acc[5]) + (acc[6] + acc[7]));
        ((f32x4*)qpart)[((size_t)c * BB + b) * D4 + t] = r;
    }

    grid.sync();

    // ---- Phase 2: every block streams one 128-row slice of one doc ----
    {
        int bn    = blk >> 2;         // 0..255
        int chunk = blk & 3;          // 0..3
        int b     = bn >> 3;          // bn / N

        f32x4 qv = {0.f, 0.f, 0.f, 0.f};
#pragma unroll
        for (int c = 0; c < QCH; ++c)
            qv += ((const f32x4*)qpart)[((size_t)c * BB + b) * D4 + t];

        const f32x4* p = (const f32x4*)(docs + ((size_t)bn * LD + (size_t)chunk * LCHUNK) * DD) + t;

        f32x4 z = {0.f, 0.f, 0.f, 0.f};
        f32x4 acc[8];
#pragma unroll
        for (int i = 0; i < 8; ++i) acc[i] = z;

#pragma unroll 2
        for (int l0 = 0; l0 < LCHUNK; l0 += 8) {
            f32x4 v[8];
#pragma unroll
            for (int k = 0; k < 8; ++k) v[k] = p[(size_t)(l0 + k) * D4];
#pragma unroll
            for (int k = 0; k < 8; ++k) acc[k] += v[k] * qv;
        }

        f32x4 r = ((acc[0] + acc[1]) + (acc[2] + acc[3])) +
                  ((acc[4] + acc[5]) + (acc[6] + acc[7]));
        float s = r.x + r.y + r.z + r.w;

        for (int off = 32; off > 0; off >>= 1)
            s += __shfl_down(s, off, 64);

        if ((t & 63) == 0) wsum[t >> 6] = s;
        __syncthreads();
        if (t == 0) {
            float sign = is_ans[bn] ? -1.f : 1.f;
            partials[blk] = (wsum[0] + wsum[1] + wsum[2]) * sign;
        }
    }

    grid.sync();

    // ---- Phase 3: block 0 reduces 1024 partials ----
    if (blk == 0) {
        float s = 0.f;
        for (int i = t; i < NBLK; i += 192)
            s += partials[i];
        for (int off = 32; off > 0; off >>= 1)
            s += __shfl_down(s, off, 64);
        if ((t & 63) == 0) wsum[t >> 6] = s;
        __syncthreads();
        if (t == 0)
            out[0] = (wsum[0] + wsum[1] + wsum[2]) * (1.f / ((float)LQ * (float)LD));
    }
}

extern "C" void kernel_launch(void* const* d_in, const int* in_sizes, int n_in,
                              void* d_out, int out_size, void* d_ws, size_t ws_size,
                              hipStream_t stream) {
    const float* q      = (const float*)d_in[0];   // [B, Lq, D] f32
    const float* docs   = (const float*)d_in[1];   // [B, N, Ld, D] f32
    const int*   is_ans = (const int*)d_in[2];     // [B, N] bool -> int
    float* out = (float*)d_out;

    float* qpart    = (float*)d_ws;                // [QCH*B*D]
    float* partials = qpart + QPART_ELEMS;         // [NBLK]

    void* args[] = { (void*)&q, (void*)&docs, (void*)&is_ans,
                     (void*)&qpart, (void*)&partials, (void*)&out };
    hipLaunchCooperativeKernel(reinterpret_cast<void*>(&fused_kernel),
                               dim3(NBLK), dim3(192), args, 0, stream);
}

// Round 4
// 533.066 us; speedup vs baseline: 1.3909x; 1.3909x over previous
//
#include <hip/hip_runtime.h>

typedef float f32x4 __attribute__((ext_vector_type(4)));

// Problem constants: B=32, N=8, Lq=256, Ld=512, D=768
#define BB 32
#define NN 8
#define LQ 256
#define LD 512
#define DD 768
#define D4 (DD / 4)                   // 192 float4 per row; row stride 3072 B

#define QCH 8                         // lq chunks in qsum kernel
#define QROWS (LQ / QCH)              // 32 rows per chunk
#define QPART_ELEMS (QCH * BB * DD)   // 196608 floats in ws

#define CH 16                         // l-chunks per (b,n) doc
#define LCHUNK (LD / CH)              // 32 rows per block
#define NBLK (BB * NN * CH)           // 4096 doc blocks

// --- forced-MLP load primitives: ONE instruction per asm statement --------
// The compiler cannot collapse or reorder volatile asm loads, so issuing 8
// of these back-to-back guarantees 8 outstanding VMEM ops per thread.
#define LOAD0(d, addr)                                                 \
    asm volatile("global_load_dwordx4 %0, %1, off"                     \
                 : "=&v"(d) : "v"(addr) : "memory")
#define LOAD3072(d, addr)                                              \
    asm volatile("global_load_dwordx4 %0, %1, off offset:3072"         \
                 : "=&v"(d) : "v"(addr) : "memory")

// Issue 8 row-loads (rows r0..r0+7) using 4 base addresses + imm offset.
#define ISSUE8(v, p, r0)                                               \
    { const f32x4* a_ = (p) + (size_t)(r0) * D4;                       \
      LOAD0(v[0], a_);            LOAD3072(v[1], a_);                  \
      const f32x4* b_ = a_ + 2 * D4;                                   \
      LOAD0(v[2], b_);            LOAD3072(v[3], b_);                  \
      const f32x4* c_ = a_ + 4 * D4;                                   \
      LOAD0(v[4], c_);            LOAD3072(v[5], c_);                  \
      const f32x4* d_ = a_ + 6 * D4;                                   \
      LOAD0(v[6], d_);            LOAD3072(v[7], d_); }

// Counted wait + scheduling fence (guide rule #18: consumers of asm-load
// results must not be hoisted above the waitcnt -> sched_barrier(0)).
#define WAITN(n)                                                       \
    asm volatile("s_waitcnt vmcnt(" #n ")" ::: "memory");              \
    __builtin_amdgcn_sched_barrier(0)

// ---------------------------------------------------------------------------
// Kernel 1: qpart[c][b][:] = sum of 32 q rows, forced 16-deep pipeline.
// grid (32, 8) x 192 threads; thread t owns float4 column t.
// ---------------------------------------------------------------------------
__global__ void __launch_bounds__(192)
qsum_kernel(const float* __restrict__ q, float* __restrict__ qpart) {
    int b = blockIdx.x;               // 0..31
    int c = blockIdx.y;               // 0..7
    int t = threadIdx.x;              // 0..191

    const f32x4* p = (const f32x4*)(q + ((size_t)b * LQ + (size_t)c * QROWS) * DD) + t;

    f32x4 va[8], vb[8];
    f32x4 acc0 = {0.f, 0.f, 0.f, 0.f}, acc1 = {0.f, 0.f, 0.f, 0.f};

    ISSUE8(va, p, 0);                 //  8 outstanding
    ISSUE8(vb, p, 8);                 // 16 outstanding
    WAITN(8);                         // va landed
#pragma unroll
    for (int k = 0; k < 8; ++k) { if (k & 1) acc1 += va[k]; else acc0 += va[k]; }
    ISSUE8(va, p, 16);
    WAITN(8);                         // vb landed
#pragma unroll
    for (int k = 0; k < 8; ++k) { if (k & 1) acc1 += vb[k]; else acc0 += vb[k]; }
    ISSUE8(vb, p, 24);
    WAITN(8);
#pragma unroll
    for (int k = 0; k < 8; ++k) { if (k & 1) acc1 += va[k]; else acc0 += va[k]; }
    WAITN(0);
#pragma unroll
    for (int k = 0; k < 8; ++k) { if (k & 1) acc1 += vb[k]; else acc0 += vb[k]; }

    ((f32x4*)qpart)[((size_t)c * BB + b) * D4 + t] = acc0 + acc1;
}

// ---------------------------------------------------------------------------
// Kernel 2: stream docs once, forced 16-deep pipeline.
// Block = (bn, l-chunk of 32 rows), 192 threads; thread t owns float4 col t.
// Ping-pong va/vb: issue 8, issue 8, wait vmcnt(8), consume, reissue.
// ---------------------------------------------------------------------------
__global__ void __launch_bounds__(192)
docs_kernel(const float* __restrict__ docs, const int* __restrict__ is_ans,
            const float* __restrict__ qpart, float* __restrict__ partials) {
    int bn    = blockIdx.x >> 4;      // 0..255
    int chunk = blockIdx.x & 15;      // 0..15
    int b     = bn >> 3;              // bn / N
    int t     = threadIdx.x;          // 0..191

    f32x4 qv = {0.f, 0.f, 0.f, 0.f};
#pragma unroll
    for (int c = 0; c < QCH; ++c)
        qv += ((const f32x4*)qpart)[((size_t)c * BB + b) * D4 + t];

    const f32x4* p = (const f32x4*)(docs + ((size_t)bn * LD + (size_t)chunk * LCHUNK) * DD) + t;

    f32x4 va[8], vb[8];
    f32x4 acc0 = {0.f, 0.f, 0.f, 0.f}, acc1 = {0.f, 0.f, 0.f, 0.f};

    ISSUE8(va, p, 0);                 //  8 outstanding
    ISSUE8(vb, p, 8);                 // 16 outstanding
    WAITN(8);                         // va landed, vb in flight
#pragma unroll
    for (int k = 0; k < 8; ++k) { if (k & 1) acc1 += va[k] * qv; else acc0 += va[k] * qv; }
    ISSUE8(va, p, 16);                // back to 16 outstanding
    WAITN(8);                         // vb landed
#pragma unroll
    for (int k = 0; k < 8; ++k) { if (k & 1) acc1 += vb[k] * qv; else acc0 += vb[k] * qv; }
    ISSUE8(vb, p, 24);
    WAITN(8);
#pragma unroll
    for (int k = 0; k < 8; ++k) { if (k & 1) acc1 += va[k] * qv; else acc0 += va[k] * qv; }
    WAITN(0);
#pragma unroll
    for (int k = 0; k < 8; ++k) { if (k & 1) acc1 += vb[k] * qv; else acc0 += vb[k] * qv; }

    f32x4 r = acc0 + acc1;
    float s = r.x + r.y + r.z + r.w;

    // wave-64 reduce
    for (int off = 32; off > 0; off >>= 1)
        s += __shfl_down(s, off, 64);

    __shared__ float wsum[3];
    if ((t & 63) == 0) wsum[t >> 6] = s;
    __syncthreads();
    if (t == 0) {
        float sign = is_ans[bn] ? -1.f : 1.f;
        partials[blockIdx.x] = (wsum[0] + wsum[1] + wsum[2]) * sign;
    }
}

// ---------------------------------------------------------------------------
// Kernel 3: reduce 4096 per-block partials, apply 1/(Lq*Ld)
// ---------------------------------------------------------------------------
__global__ void __launch_bounds__(256)
finish_kernel(const float* __restrict__ partials, float* __restrict__ out) {
    int t = threadIdx.x;
    float s = 0.f;
#pragma unroll
    for (int i = 0; i < NBLK; i += 256)
        s += partials[i + t];
    for (int off = 32; off > 0; off >>= 1)
        s += __shfl_down(s, off, 64);
    __shared__ float wsum[4];
    if ((t & 63) == 0) wsum[t >> 6] = s;
    __syncthreads();
    if (t == 0)
        out[0] = (wsum[0] + wsum[1] + wsum[2] + wsum[3]) * (1.f / ((float)LQ * (float)LD));
}

extern "C" void kernel_launch(void* const* d_in, const int* in_sizes, int n_in,
                              void* d_out, int out_size, void* d_ws, size_t ws_size,
                              hipStream_t stream) {
    const float* q      = (const float*)d_in[0];   // [B, Lq, D] f32
    const float* docs   = (const float*)d_in[1];   // [B, N, Ld, D] f32
    const int*   is_ans = (const int*)d_in[2];     // [B, N] bool -> int
    float* out = (float*)d_out;

    float* qpart    = (float*)d_ws;                // [QCH*B*D]
    float* partials = qpart + QPART_ELEMS;         // [NBLK]

    qsum_kernel<<<dim3(BB, QCH), 192, 0, stream>>>(q, qpart);
    docs_kernel<<<dim3(NBLK), 192, 0, stream>>>(docs, is_ans, qpart, partials);
    finish_kernel<<<1, 256, 0, stream>>>(partials, out);
}